// Round 3
// baseline (436.469 us; speedup 1.0000x reference)
//
#include <hip/hip_runtime.h>

// LSTMSoftAttention on MI355X — R3.
// Shapes: H=1024, N=2048, T=2048, B=16, all fp32.
//
// R3 changes vs R2:
//  * k_main: explicit next-row register prefetch (8 KB in flight per wave
//    across the tanh+butterfly phase -> HBM never idles at 8 waves/CU).
//  * k_main: block-level context reduction via 32 KB LDS (single barrier at
//    kernel END) -> c_part traffic 33.5 MB -> 8.4 MB.
//  * k_linv + k_finc + k_fina merged into one k_fin (5 launches -> 3).
//
// Workspace (floats):
//   dec_fea 32768 | p 32768 | l_part 64*16 | c_part 64*16*2048

#define HH 1024
#define NNF 2048
#define TTT 2048
#define BB 16
#define NCHUNK 64     // blocks along T in k_main; 32 rows per block
#define RPW 8         // rows per wave

#define WS_DECFEA 0
#define WS_P      (BB * NNF)                  // 32768
#define WS_LPART  (WS_P + TTT * BB)           // 65536
#define WS_CPART  (WS_LPART + NCHUNK * BB)    // 66560 (66560*4 % 16 == 0)

__device__ __forceinline__ float tanh_fast(float x) {
    // tanh(x) = 1 - 2/(exp(2x)+1); saturates correctly at +-inf.
    float e = __expf(2.0f * x);
    return 1.0f - 2.0f * __builtin_amdgcn_rcpf(e + 1.0f);
}

// dec_fea[b,n] = dot(dec[b,:], Wd[n,:]) + bd[n]
// One wave per n; each wave computes all 16 b outputs so Wd is read once (8 MB HBM).
__global__ __launch_bounds__(256) void k_decfea(const float* __restrict__ dec,
                                                const float* __restrict__ Wd,
                                                const float* __restrict__ bd,
                                                float* __restrict__ dec_fea) {
    const int n    = (blockIdx.x * 256 + threadIdx.x) >> 6;  // 0..2047
    const int lane = threadIdx.x & 63;
    const float* wr = Wd + (size_t)n * HH;

    float acc[BB];
#pragma unroll
    for (int b = 0; b < BB; ++b) acc[b] = 0.0f;

#pragma unroll
    for (int it = 0; it < 4; ++it) {
        const int h = it * 256 + lane * 4;
        const float4 w4 = *(const float4*)(wr + h);
#pragma unroll
        for (int b = 0; b < BB; ++b) {
            const float4 d4 = *(const float4*)(dec + b * HH + h);
            acc[b] = fmaf(w4.x, d4.x, acc[b]);
            acc[b] = fmaf(w4.y, d4.y, acc[b]);
            acc[b] = fmaf(w4.z, d4.z, acc[b]);
            acc[b] = fmaf(w4.w, d4.w, acc[b]);
        }
    }
#pragma unroll
    for (int b = 0; b < BB; ++b) {
#pragma unroll
        for (int off = 32; off; off >>= 1) acc[b] += __shfl_xor(acc[b], off, 64);
    }
    if (lane == 0) {
        const float bias = bd[n];
#pragma unroll
        for (int b = 0; b < BB; ++b) dec_fea[b * NNF + n] = acc[b] + bias;
    }
}

// Fused scores + unnormalized-softmax context accumulation.
// Grid (NCHUNK, BB), 256 threads = 4 waves. Wave w owns rows
// t = chunk*32 + w*8 .. +7 for batch b; lane covers 8 float4 segments/row.
// Barrier-free hot loop with explicit next-row prefetch; one block-level
// LDS reduction of the context accumulators at the end.
__global__ __launch_bounds__(256, 2) void k_main(const float* __restrict__ enc,
                                                 const int* __restrict__ mask,
                                                 const float* __restrict__ cov,
                                                 const float* __restrict__ wc,
                                                 const float* __restrict__ v,
                                                 float* __restrict__ ws) {
    const int b     = blockIdx.y;
    const int chunk = blockIdx.x;
    const int tid   = threadIdx.x;
    const int lane  = tid & 63;
    const int w     = tid >> 6;
    const int t0    = chunk * (4 * RPW) + w * RPW;
    const int nb    = lane * 4;   // lane base within each 256-float segment

    const float* dec_fea = ws + WS_DECFEA;
    float* ws_p     = ws + WS_P;
    float* ws_lpart = ws + WS_LPART;
    float* cpart    = ws + WS_CPART;

    float4 d[8], wv[8], vv[8], c[8];
#pragma unroll
    for (int s = 0; s < 8; ++s) {
        const int n = s * 256 + nb;
        d[s]  = *(const float4*)(dec_fea + b * NNF + n);
        wv[s] = *(const float4*)(wc + n);
        vv[s] = *(const float4*)(v + n);
        c[s]  = make_float4(0.f, 0.f, 0.f, 0.f);
    }

    float l_loc = 0.0f;

    // prefetch row t0
    float4 f[8];
    {
        const float* row = enc + ((size_t)t0 * BB + b) * NNF;
#pragma unroll
        for (int s = 0; s < 8; ++s) f[s] = *(const float4*)(row + s * 256 + nb);
    }

#pragma unroll
    for (int r = 0; r < RPW; ++r) {
        const int t = t0 + r;
        // issue next-row loads BEFORE consuming f: keeps 8 KB/wave in flight
        float4 fn[8];
        if (r + 1 < RPW) {
            const float* rowN = enc + ((size_t)(t + 1) * BB + b) * NNF;
#pragma unroll
            for (int s = 0; s < 8; ++s) fn[s] = *(const float4*)(rowN + s * 256 + nb);
        }
        const float cv = cov[t * BB + b];

        float sa = 0.0f;
#pragma unroll
        for (int s = 0; s < 8; ++s) {
            float a;
            a = fmaf(cv, wv[s].x, f[s].x + d[s].x); sa = fmaf(tanh_fast(a), vv[s].x, sa);
            a = fmaf(cv, wv[s].y, f[s].y + d[s].y); sa = fmaf(tanh_fast(a), vv[s].y, sa);
            a = fmaf(cv, wv[s].z, f[s].z + d[s].z); sa = fmaf(tanh_fast(a), vv[s].z, sa);
            a = fmaf(cv, wv[s].w, f[s].w + d[s].w); sa = fmaf(tanh_fast(a), vv[s].w, sa);
        }
        // full-wave butterfly: every lane ends with the row score
#pragma unroll
        for (int off = 32; off; off >>= 1) sa += __shfl_xor(sa, off, 64);

        const bool pad = mask[t * BB + b] != 0;
        const float p = pad ? 0.0f : __expf(sa);
        l_loc += p;
#pragma unroll
        for (int s = 0; s < 8; ++s) {
            c[s].x = fmaf(p, f[s].x, c[s].x);
            c[s].y = fmaf(p, f[s].y, c[s].y);
            c[s].z = fmaf(p, f[s].z, c[s].z);
            c[s].w = fmaf(p, f[s].w, c[s].w);
        }
        if (lane == 0) ws_p[t * BB + b] = p;
#pragma unroll
        for (int s = 0; s < 8; ++s) f[s] = fn[s];
    }

    // ---- block-level context reduce through LDS (single end-of-kernel barrier)
    __shared__ float cbuf[4][NNF];   // 32 KB
    __shared__ float lred[4];
#pragma unroll
    for (int s = 0; s < 8; ++s) *(float4*)(&cbuf[w][s * 256 + nb]) = c[s];
    if (lane == 0) lred[w] = l_loc;
    __syncthreads();

    // block output: 2048 floats; thread tid sums 4 waves for its 2 segments
    float* cp = cpart + (size_t)(chunk * BB + b) * NNF;
#pragma unroll
    for (int half = 0; half < 2; ++half) {
        const int e = half * 1024 + tid * 4;
        float4 s0 = *(const float4*)(&cbuf[0][e]);
        float4 s1 = *(const float4*)(&cbuf[1][e]);
        float4 s2 = *(const float4*)(&cbuf[2][e]);
        float4 s3 = *(const float4*)(&cbuf[3][e]);
        float4 o;
        o.x = (s0.x + s1.x) + (s2.x + s3.x);
        o.y = (s0.y + s1.y) + (s2.y + s3.y);
        o.z = (s0.z + s1.z) + (s2.z + s3.z);
        o.w = (s0.w + s1.w) + (s2.w + s3.w);
        *(float4*)(cp + e) = o;
    }
    if (tid == 0)
        ws_lpart[chunk * BB + b] = (lred[0] + lred[1]) + (lred[2] + lred[3]);
}

// Merged finalize: every block redundantly computes l_inv[16] from the 4 KB
// l_part, then blocks 0..31 produce c and blocks 32..159 produce attn+cov.
__global__ __launch_bounds__(256) void k_fin(const float* __restrict__ ws,
                                             const float* __restrict__ cov,
                                             float* __restrict__ out_c,
                                             float* __restrict__ out_attn,
                                             float* __restrict__ out_cov) {
    const int tid = threadIdx.x;
    __shared__ float pr[16][17];
    __shared__ float linv[16];
    {
        const int bb = tid & 15;
        const int g  = tid >> 4;       // 16 groups, each covers 4 chunks
        float s = 0.0f;
#pragma unroll
        for (int k = 0; k < 4; ++k)
            s += ws[WS_LPART + (g * 4 + k) * BB + bb];
        pr[g][bb] = s;
    }
    __syncthreads();
    if (tid < 16) {
        float tot = 0.0f;
#pragma unroll
        for (int g = 0; g < 16; ++g) tot += pr[g][tid];
        linv[tid] = 1.0f / tot;
    }
    __syncthreads();

    if (blockIdx.x < 32) {
        // context: block k covers output elements [k*1024, (k+1)*1024)
        const int k = blockIdx.x;
        const int b = k >> 1;
        const int n = (k & 1) * 1024 + tid * 4;
        float4 s = {0.f, 0.f, 0.f, 0.f};
#pragma unroll 8
        for (int j = 0; j < NCHUNK; ++j) {
            const float4 a = *(const float4*)(ws + WS_CPART + (size_t)(j * BB + b) * NNF + n);
            s.x += a.x; s.y += a.y; s.z += a.z; s.w += a.w;
        }
        const float li = linv[b];
        s.x *= li; s.y *= li; s.z *= li; s.w *= li;
        *(float4*)(out_c + b * NNF + n) = s;
    } else {
        // attn + coverage: idx = t*B + b
        const int idx = (blockIdx.x - 32) * 256 + tid;
        const int b = idx & (BB - 1);
        const float a = ws[WS_P + idx] * linv[b];
        out_attn[idx] = a;
        out_cov[idx] = cov[idx] + a;
    }
}

extern "C" void kernel_launch(void* const* d_in, const int* in_sizes, int n_in,
                              void* d_out, int out_size, void* d_ws, size_t ws_size,
                              hipStream_t stream) {
    const float* dec  = (const float*)d_in[0];
    const float* enc  = (const float*)d_in[1];
    const int*   mask = (const int*)d_in[2];
    const float* cov  = (const float*)d_in[3];
    const float* Wd   = (const float*)d_in[4];
    const float* bd   = (const float*)d_in[5];
    const float* wc   = (const float*)d_in[6];
    const float* v    = (const float*)d_in[7];
    float* ws  = (float*)d_ws;
    float* out = (float*)d_out;

    float* out_c    = out;                 // (B, N)   32768
    float* out_attn = out + BB * NNF;      // (T, B)   32768
    float* out_cov  = out_attn + TTT * BB; // (T, B)   32768

    // 1. dec_fea: 2048 waves (one per n) -> 512 blocks of 256
    k_decfea<<<512, 256, 0, stream>>>(dec, Wd, bd, ws + WS_DECFEA);

    // 2. fused single pass over enc (256 MiB), prefetched, barrier-free loop
    dim3 g2(NCHUNK, BB);
    k_main<<<g2, 256, 0, stream>>>(enc, mask, cov, wc, v, ws);

    // 3. merged finalize (l_inv + context sum + attn/coverage)
    k_fin<<<160, 256, 0, stream>>>(ws, cov, out_c, out_attn, out_cov);
}

// Round 5
// 409.071 us; speedup vs baseline: 1.0670x; 1.0670x over previous
//
#include <hip/hip_runtime.h>

// LSTMSoftAttention on MI355X — R5 (R4 with compile fix).
// Shapes: H=1024, N=2048, T=2048, B=16, all fp32.
//
// Theory (from R1>R2>R3 regression data): this kernel is a latency/BW
// streaming problem — occupancy and small VGPR count dominate. R2/R3 kept
// 96 VGPRs of per-lane constants (dec_fea/wc/v) in registers, capping
// occupancy at 8 waves/CU and likely spilling in R3.
// Now: constants live in 24 KB LDS shared by the block's 4 waves (all same b);
// registers are just c[8]+f[8] (~100 VGPR) -> launch_bounds(256,3),
// 12 waves/CU, barrier-free hot loop, nontemporal enc loads.
// R5 fix: __builtin_nontemporal_load needs a native Clang vector type, not
// HIP_vector_type<float,4> — use ext_vector_type(4) float.
//
// Workspace (floats):
//   dec_fea 32768 | p 32768 | l_part 64*16 | c_part 64*16*2048

#define HH 1024
#define NNF 2048
#define TTT 2048
#define BB 16
#define NCHUNK 64     // blocks along T in k_main; 32 rows per block
#define RPW 8         // rows per wave

#define WS_DECFEA 0
#define WS_P      (BB * NNF)                  // 32768
#define WS_LPART  (WS_P + TTT * BB)           // 65536
#define WS_CPART  (WS_LPART + NCHUNK * BB)    // 66560 (66560*4 % 16 == 0)

typedef float fx4 __attribute__((ext_vector_type(4)));

__device__ __forceinline__ float tanh_fast(float x) {
    // tanh(x) = 1 - 2/(exp(2x)+1); saturates correctly at +-inf.
    float e = __expf(2.0f * x);
    return 1.0f - 2.0f * __builtin_amdgcn_rcpf(e + 1.0f);
}

// dec_fea[b,n] = dot(dec[b,:], Wd[n,:]) + bd[n]
// One wave per n; each wave computes all 16 b outputs so Wd is read once (8 MB HBM).
__global__ __launch_bounds__(256) void k_decfea(const float* __restrict__ dec,
                                                const float* __restrict__ Wd,
                                                const float* __restrict__ bd,
                                                float* __restrict__ dec_fea) {
    const int n    = (blockIdx.x * 256 + threadIdx.x) >> 6;  // 0..2047
    const int lane = threadIdx.x & 63;
    const float* wr = Wd + (size_t)n * HH;

    float acc[BB];
#pragma unroll
    for (int b = 0; b < BB; ++b) acc[b] = 0.0f;

#pragma unroll
    for (int it = 0; it < 4; ++it) {
        const int h = it * 256 + lane * 4;
        const float4 w4 = *(const float4*)(wr + h);
#pragma unroll
        for (int b = 0; b < BB; ++b) {
            const float4 d4 = *(const float4*)(dec + b * HH + h);
            acc[b] = fmaf(w4.x, d4.x, acc[b]);
            acc[b] = fmaf(w4.y, d4.y, acc[b]);
            acc[b] = fmaf(w4.z, d4.z, acc[b]);
            acc[b] = fmaf(w4.w, d4.w, acc[b]);
        }
    }
#pragma unroll
    for (int b = 0; b < BB; ++b) {
#pragma unroll
        for (int off = 32; off; off >>= 1) acc[b] += __shfl_xor(acc[b], off, 64);
    }
    if (lane == 0) {
        const float bias = bd[n];
#pragma unroll
        for (int b = 0; b < BB; ++b) dec_fea[b * NNF + n] = acc[b] + bias;
    }
}

// Fused scores + unnormalized-softmax context accumulation.
// Grid (NCHUNK, BB), 256 threads = 4 waves; wave w owns rows
// t = chunk*32 + w*8 .. +7 of batch b. Constants (dec_fea|wc|v for this b)
// live in LDS; hot loop is barrier-free; block-level context reduction at
// the end reuses the same LDS buffer.
__global__ __launch_bounds__(256, 3) void k_main(const float* __restrict__ enc,
                                                 const int* __restrict__ mask,
                                                 const float* __restrict__ cov,
                                                 const float* __restrict__ wc,
                                                 const float* __restrict__ v,
                                                 float* __restrict__ ws) {
    const int b     = blockIdx.y;
    const int chunk = blockIdx.x;
    const int tid   = threadIdx.x;
    const int lane  = tid & 63;
    const int w     = tid >> 6;
    const int nb    = lane * 4;   // lane base within each 256-float segment

    __shared__ float smem[4 * NNF];   // 32 KB: [d | wv | vv | spare] then c-reduce
    __shared__ float lred[4];

    float* ws_p     = ws + WS_P;
    float* ws_lpart = ws + WS_LPART;
    float* cpart    = ws + WS_CPART;

    // stage per-b constants into LDS (each thread: 2 float4 per array)
    {
        const float* dec_fea = ws + WS_DECFEA + b * NNF;
#pragma unroll
        for (int i = tid * 4; i < NNF; i += 1024) {
            *(float4*)&smem[i]            = *(const float4*)(dec_fea + i);
            *(float4*)&smem[NNF + i]      = *(const float4*)(wc + i);
            *(float4*)&smem[2 * NNF + i]  = *(const float4*)(v + i);
        }
    }
    __syncthreads();

    fx4 c[8];
#pragma unroll
    for (int s = 0; s < 8; ++s) c[s] = (fx4)0.0f;
    float l_loc = 0.0f;

    const int tbase = chunk * (4 * RPW) + w * RPW;

    for (int r = 0; r < RPW; ++r) {
        const int t = tbase + r;
        const float* row = enc + ((size_t)t * BB + b) * NNF + nb;
        fx4 f[8];
#pragma unroll
        for (int s = 0; s < 8; ++s)
            f[s] = __builtin_nontemporal_load((const fx4*)(row + s * 256));
        const float cv = cov[t * BB + b];

        float sa = 0.0f;
#pragma unroll
        for (int s = 0; s < 8; ++s) {
            const fx4 dd = *(const fx4*)&smem[s * 256 + nb];
            const fx4 ww = *(const fx4*)&smem[NNF + s * 256 + nb];
            const fx4 vx = *(const fx4*)&smem[2 * NNF + s * 256 + nb];
            float a;
            a = fmaf(cv, ww.x, f[s].x + dd.x); sa = fmaf(tanh_fast(a), vx.x, sa);
            a = fmaf(cv, ww.y, f[s].y + dd.y); sa = fmaf(tanh_fast(a), vx.y, sa);
            a = fmaf(cv, ww.z, f[s].z + dd.z); sa = fmaf(tanh_fast(a), vx.z, sa);
            a = fmaf(cv, ww.w, f[s].w + dd.w); sa = fmaf(tanh_fast(a), vx.w, sa);
        }
        // full-wave butterfly: every lane ends with the row score
#pragma unroll
        for (int off = 32; off; off >>= 1) sa += __shfl_xor(sa, off, 64);

        const float p = (mask[t * BB + b] != 0) ? 0.0f : __expf(sa);
        l_loc += p;
#pragma unroll
        for (int s = 0; s < 8; ++s) {
            c[s].x = fmaf(p, f[s].x, c[s].x);
            c[s].y = fmaf(p, f[s].y, c[s].y);
            c[s].z = fmaf(p, f[s].z, c[s].z);
            c[s].w = fmaf(p, f[s].w, c[s].w);
        }
        if (lane == 0) ws_p[t * BB + b] = p;
    }

    // ---- block-level context reduce, reusing smem (constants dead now)
    __syncthreads();   // all waves done READING constants
#pragma unroll
    for (int s = 0; s < 8; ++s) *(fx4*)&smem[w * NNF + s * 256 + nb] = c[s];
    if (lane == 0) lred[w] = l_loc;
    __syncthreads();

    float* cp = cpart + (size_t)(chunk * BB + b) * NNF;
#pragma unroll
    for (int half = 0; half < 2; ++half) {
        const int e = half * 1024 + tid * 4;
        fx4 s0 = *(const fx4*)&smem[0 * NNF + e];
        fx4 s1 = *(const fx4*)&smem[1 * NNF + e];
        fx4 s2 = *(const fx4*)&smem[2 * NNF + e];
        fx4 s3 = *(const fx4*)&smem[3 * NNF + e];
        fx4 o = (s0 + s1) + (s2 + s3);
        *(fx4*)(cp + e) = o;
    }
    if (tid == 0)
        ws_lpart[chunk * BB + b] = (lred[0] + lred[1]) + (lred[2] + lred[3]);
}

// Merged finalize: every block redundantly computes l_inv[16] from the 4 KB
// l_part, then blocks 0..31 produce c and blocks 32..159 produce attn+cov.
__global__ __launch_bounds__(256) void k_fin(const float* __restrict__ ws,
                                             const float* __restrict__ cov,
                                             float* __restrict__ out_c,
                                             float* __restrict__ out_attn,
                                             float* __restrict__ out_cov) {
    const int tid = threadIdx.x;
    __shared__ float pr[16][17];
    __shared__ float linv[16];
    {
        const int bb = tid & 15;
        const int g  = tid >> 4;       // 16 groups, each covers 4 chunks
        float s = 0.0f;
#pragma unroll
        for (int k = 0; k < 4; ++k)
            s += ws[WS_LPART + (g * 4 + k) * BB + bb];
        pr[g][bb] = s;
    }
    __syncthreads();
    if (tid < 16) {
        float tot = 0.0f;
#pragma unroll
        for (int g = 0; g < 16; ++g) tot += pr[g][tid];
        linv[tid] = 1.0f / tot;
    }
    __syncthreads();

    if (blockIdx.x < 32) {
        // context: block k covers output elements [k*1024, (k+1)*1024)
        const int k = blockIdx.x;
        const int b = k >> 1;
        const int n = (k & 1) * 1024 + tid * 4;
        float4 s = {0.f, 0.f, 0.f, 0.f};
#pragma unroll 8
        for (int j = 0; j < NCHUNK; ++j) {
            const float4 a = *(const float4*)(ws + WS_CPART + (size_t)(j * BB + b) * NNF + n);
            s.x += a.x; s.y += a.y; s.z += a.z; s.w += a.w;
        }
        const float li = linv[b];
        s.x *= li; s.y *= li; s.z *= li; s.w *= li;
        *(float4*)(out_c + b * NNF + n) = s;
    } else {
        // attn + coverage: idx = t*B + b
        const int idx = (blockIdx.x - 32) * 256 + tid;
        const int b = idx & (BB - 1);
        const float a = ws[WS_P + idx] * linv[b];
        out_attn[idx] = a;
        out_cov[idx] = cov[idx] + a;
    }
}

extern "C" void kernel_launch(void* const* d_in, const int* in_sizes, int n_in,
                              void* d_out, int out_size, void* d_ws, size_t ws_size,
                              hipStream_t stream) {
    const float* dec  = (const float*)d_in[0];
    const float* enc  = (const float*)d_in[1];
    const int*   mask = (const int*)d_in[2];
    const float* cov  = (const float*)d_in[3];
    const float* Wd   = (const float*)d_in[4];
    const float* bd   = (const float*)d_in[5];
    const float* wc   = (const float*)d_in[6];
    const float* v    = (const float*)d_in[7];
    float* ws  = (float*)d_ws;
    float* out = (float*)d_out;

    float* out_c    = out;                 // (B, N)   32768
    float* out_attn = out + BB * NNF;      // (T, B)   32768
    float* out_cov  = out_attn + TTT * BB; // (T, B)   32768

    // 1. dec_fea: 2048 waves (one per n) -> 512 blocks of 256
    k_decfea<<<512, 256, 0, stream>>>(dec, Wd, bd, ws + WS_DECFEA);

    // 2. fused single pass over enc (256 MiB), LDS constants, barrier-free loop
    dim3 g2(NCHUNK, BB);
    k_main<<<g2, 256, 0, stream>>>(enc, mask, cov, wc, v, ws);

    // 3. merged finalize (l_inv + context sum + attn/coverage)
    k_fin<<<160, 256, 0, stream>>>(ws, cov, out_c, out_attn, out_cov);
}